// Round 3
// baseline (421.121 us; speedup 1.0000x reference)
//
#include <hip/hip_runtime.h>
#include <hip/hip_bf16.h>
#include <math.h>

#define NB 64      // batch
#define NN 576     // patches
#define ND 512     // dim
#define NM 16      // nouns
#define QPB 9      // fine blocks per batch element (64 patches each)
#define NPB 64     // patches per fine block
#define NWF 8      // waves per fine block (D-split)
#define DPW 64     // d-range per wave
#define KPOS 5
#define TINV 14.2857142857142857f   // 1/0.07

#define WS_REC_OFF 4096             // after 64*64 scores
#define RECSZ 144                   // floats per fine-block record
#define CNT_IDX (WS_REC_OFF + NB * QPB * RECSZ)   // 87040
#define NBLK (NB * QPB + NB)        // 640

#define FINF __builtin_inff()

// insert v into desc-sorted 5-list (constant indices only -> stays in VGPRs)
__device__ __forceinline__ void ins5(float (&a)[5], float v) {
  if (v > a[4]) {
    a[4] = v;
    if (a[4] > a[3]) { float x = a[4]; a[4] = a[3]; a[3] = x; }
    if (a[3] > a[2]) { float x = a[3]; a[3] = a[2]; a[2] = x; }
    if (a[2] > a[1]) { float x = a[2]; a[2] = a[1]; a[1] = x; }
    if (a[1] > a[0]) { float x = a[1]; a[1] = a[0]; a[0] = x; }
  }
}

// top-5 of union of two desc-sorted 5-lists, branch-free fixed-index rank merge
__device__ __forceinline__ void merge5(float (&a)[5], const float (&b)[5]) {
  float r[5];
#pragma unroll
  for (int k = 0; k < 5; ++k) {
    float best = -FINF;
#pragma unroll
    for (int i = 0; i <= k + 1; ++i) {
      const int j = k + 1 - i;
      const float av = (i == 0) ? FINF : a[i - 1];
      const float bv = (j == 0) ? FINF : b[j - 1];
      best = fmaxf(best, fminf(av, bv));
    }
    r[k] = best;
  }
#pragma unroll
  for (int k = 0; k < 5; ++k) a[k] = r[k];
}

__device__ __forceinline__ void merge5_shfl(float (&a)[5], int msk) {
  float o[5];
#pragma unroll
  for (int k = 0; k < 5; ++k) o[k] = __shfl_xor(a[k], msk, 64);
  merge5(a, o);
}

__global__ __launch_bounds__(512, 6) void k_all(
    const float* __restrict__ patch, const float* __restrict__ noun,
    const float* __restrict__ gimg, const float* __restrict__ gtxt,
    const float* __restrict__ lscale, const int* __restrict__ idx,
    float* __restrict__ ws, float* __restrict__ out) {
  const int blk = blockIdx.x;
  const int t = threadIdx.x;
  const int lane = t & 63;

  __shared__ float L[NWF * 1024 + NM * 65];   // 9232 floats = 36.9 KB
  __shared__ unsigned int winflag;

  if (blk < NB * QPB) {
    // ================= fine block: b, 64-patch slice =================
    const int b = blk / QPB;
    const int quad = blk - b * QPB;
    const int wv = __builtin_amdgcn_readfirstlane(t >> 6);  // 0..7, uniform

    // lane owns one patch row; wave owns d-range [wv*64, wv*64+64)
    const float4* prow = (const float4*)(patch +
        ((size_t)(b * NN + quad * NPB + lane)) * ND + wv * DPW);
    const float* nbase = noun + (size_t)b * NM * ND + wv * DPW;

    float acc[NM];
#pragma unroll
    for (int m = 0; m < NM; ++m) acc[m] = 0.f;

#pragma unroll
    for (int c = 0; c < 2; ++c) {        // two 32-float chunks
      float pf[32];
#pragma unroll
      for (int k = 0; k < 8; ++k) {
        const float4 v = prow[c * 8 + k];  // per-lane contiguous 128 B
        pf[4 * k] = v.x; pf[4 * k + 1] = v.y; pf[4 * k + 2] = v.z; pf[4 * k + 3] = v.w;
      }
      const float* nc = nbase + c * 32;    // wave-uniform -> s_load
#pragma unroll 4
      for (int m = 0; m < NM; ++m) {
        const float* np_ = nc + m * ND;
        float s0 = 0.f, s1 = 0.f;
#pragma unroll
        for (int d = 0; d < 32; d += 2) {
          s0 += pf[d] * np_[d];
          s1 += pf[d + 1] * np_[d + 1];
        }
        acc[m] += s0 + s1;
      }
    }

    // ---- cross-wave reduction: 8 d-partials per (m, patch) ----
#pragma unroll
    for (int m = 0; m < NM; ++m) L[wv * 1024 + m * 64 + lane] = acc[m];
    __syncthreads();
    float* simL = &L[NWF * 1024];
    for (int i = t; i < 1024; i += 512) {
      float s = 0.f;
#pragma unroll
      for (int w = 0; w < NWF; ++w) s += L[w * 1024 + i];
      simL[(i >> 6) * 65 + (i & 63)] = s * TINV;   // scaled sim
    }
    __syncthreads();

    float* rec = ws + WS_REC_OFF + (size_t)blk * RECSZ;
    if (wv == 1) {
      // ---- mask partials: softplus sum + top5 of pooled/T over 64 patches ----
      float x = 0.f;
#pragma unroll
      for (int m = 0; m < NM; ++m) x += simL[m * 65 + lane];
      x *= (1.f / 16.f);
      float sxp = (x > 0.f) ? (x + log1pf(expf(-x))) : log1pf(expf(x));
      float t5[5] = {x, -FINF, -FINF, -FINF, -FINF};
#pragma unroll
      for (int msk = 1; msk < 64; msk <<= 1) {
        sxp += __shfl_xor(sxp, msk, 64);
        merge5_shfl(t5, msk);
      }
      if (lane == 0) {
        rec[128] = sxp;
#pragma unroll
        for (int k = 0; k < 5; ++k) rec[129 + k] = t5[k];
      }
    } else if (wv == 0) {
      // ---- per-noun row stats over 64 cols (16 rows x 4 segments) ----
      const int r_ = lane & 15;
      const int h = lane >> 4;
      const float* row = &simL[r_ * 65 + h * 16];
      float mx = -FINF;
#pragma unroll
      for (int k = 0; k < 16; ++k) mx = fmaxf(mx, row[k]);
      mx = fmaxf(mx, __shfl_xor(mx, 16, 64));
      mx = fmaxf(mx, __shfl_xor(mx, 32, 64));
      float se = 0.f;
      float r5[5] = {-FINF, -FINF, -FINF, -FINF, -FINF};
#pragma unroll
      for (int k = 0; k < 16; ++k) {
        const float v = row[k];
        se += expf(v - mx);
        ins5(r5, v);
      }
      se += __shfl_xor(se, 16, 64);
      se += __shfl_xor(se, 32, 64);
      merge5_shfl(r5, 16);
      merge5_shfl(r5, 32);
      if (h == 0) {
        float* rr = rec + r_ * 8;
        rr[0] = mx;
        rr[1] = se;
#pragma unroll
        for (int k = 0; k < 5; ++k) rr[2 + k] = r5[k];
      }
    }
  } else {
    // ================= score block: scores[i][j] = <img_i, txt_j> =================
    const int i = blk - NB * QPB;
    const int dq = t >> 6;   // 0..7 d-split
    const float4* ip = (const float4*)(gimg + (size_t)i * ND + dq * DPW);
    const float4* tp = (const float4*)(gtxt + (size_t)lane * ND + dq * DPW);
    float a = 0.f;
#pragma unroll
    for (int q = 0; q < DPW / 4; ++q) {
      const float4 x = ip[q];
      const float4 y = tp[q];
      a += x.x * y.x + x.y * y.y + x.z * y.z + x.w * y.w;
    }
    L[dq * 64 + lane] = a;
    __syncthreads();
    if (t < 64) {
      float s = 0.f;
#pragma unroll
      for (int w = 0; w < NWF; ++w) s += L[w * 64 + t];
      ws[i * 64 + t] = s;
    }
  }

  // ================= completion counter; last block runs the finale =================
  __syncthreads();
  __threadfence();                       // publish this thread's ws writes device-wide
  if (t == 0) {
    const unsigned old = atomicAdd((unsigned int*)(ws + CNT_IDX), 1u);
    winflag = (old == NBLK - 1) ? 1u : 0u;
  }
  __syncthreads();
  if (!winflag) return;
  __threadfence();                       // acquire: see all other blocks' writes

  // ---- Part A: contrastive merge over (b, m) pairs; Part B: mask merge per b ----
  const float* recs = ws + WS_REC_OFF;
  float local = 0.f;
  for (int i = t; i < NB * NM; i += 512) {
    const int b = i >> 4, m = i & 15;
    const float* base = recs + (size_t)b * QPB * RECSZ + m * 8;
    float mx = -FINF;
#pragma unroll
    for (int q = 0; q < QPB; ++q) mx = fmaxf(mx, base[q * RECSZ]);
    float S = 0.f;
    float t5[5] = {-FINF, -FINF, -FINF, -FINF, -FINF};
#pragma unroll
    for (int q = 0; q < QPB; ++q) {
      S += base[q * RECSZ + 1] * expf(base[q * RECSZ] - mx);
#pragma unroll
      for (int k = 0; k < 5; ++k) ins5(t5, base[q * RECSZ + 2 + k]);
    }
    const float st = t5[0] + t5[1] + t5[2] + t5[3] + t5[4];
    local += (KPOS * (mx + logf(S)) - st) * (0.6f / (float)(NB * NM));
  }
  if (t < NB) {
    const float* base = recs + (size_t)t * QPB * RECSZ + 128;
    float sp = 0.f;
    float u5[5] = {-FINF, -FINF, -FINF, -FINF, -FINF};
#pragma unroll
    for (int q = 0; q < QPB; ++q) {
      sp += base[q * RECSZ];
#pragma unroll
      for (int k = 0; k < 5; ++k) ins5(u5, base[q * RECSZ + 1 + k]);
    }
    const float st = u5[0] + u5[1] + u5[2] + u5[3] + u5[4];
    local += (sp - st) * (0.4f / (float)(NB * NN));
  }
#pragma unroll
  for (int msk = 1; msk < 64; msk <<= 1) local += __shfl_xor(local, msk, 64);
  __syncthreads();                      // L free for reuse now
  if (lane == 0) L[t >> 6] = local;
  __syncthreads();
  if (t == 0) {
    float s = 0.f;
#pragma unroll
    for (int w = 0; w < NWF; ++w) s += L[w];
    out[2] = s;
  }
  __syncthreads();

  // ---- Part C: loss_c (CLIP bi-directional CE) + loss_t (triplet) ----
  float* S_ = &L[0];                     // 64 x 65 padded score tile
  for (int i = t; i < 4096; i += 512) S_[(i >> 6) * 65 + (i & 63)] = ws[i];
  __syncthreads();
  float* dgp = &L[4160];
  int* idl = (int*)&L[4224];
  if (t < 64) { dgp[t] = S_[t * 66]; idl[t] = idx[t]; }
  __syncthreads();
  if (t < 64) {                          // exactly wave 0
    const float sc = lscale[0];
    float mR = -FINF, mC = -FINF;
    for (int j = 0; j < 64; ++j) {
      mR = fmaxf(mR, sc * S_[t * 65 + j]);
      mC = fmaxf(mC, sc * S_[j * 65 + t]);
    }
    float seR = 0.f, seC = 0.f;
    for (int j = 0; j < 64; ++j) {
      seR += expf(sc * S_[t * 65 + j] - mR);
      seC += expf(sc * S_[j * 65 + t] - mC);
    }
    const float lseR = mR + logf(seR);
    const float lseC = mC + logf(seC);
    const int myid = idl[t];
    const float di = dgp[t];
    float ps = 0.f, trow = 0.f, tcol = 0.f, cs = 0.f, ci = 0.f;
    for (int j = 0; j < 64; ++j) {
      const float sv = S_[t * 65 + j];
      const float svT = S_[j * 65 + t];
      if (idl[j] == myid) {
        ps += 1.f;
        trow += sc * sv - lseR;
        tcol += sc * svT - lseC;
      }
      if (j != t) {
        cs += fmaxf(0.f, 0.1f + sv - di);
        ci += fmaxf(0.f, 0.1f + sv - dgp[j]);
      }
    }
    float vc = -(trow + tcol) / ps;
    float vt = cs + ci;
#pragma unroll
    for (int msk = 1; msk < 64; msk <<= 1) {
      vc += __shfl_xor(vc, msk, 64);
      vt += __shfl_xor(vt, msk, 64);
    }
    if (t == 0) {
      out[0] = vc * (0.5f / 64.f);
      out[1] = vt * 0.5f;
    }
  }
}

extern "C" void kernel_launch(void* const* d_in, const int* in_sizes, int n_in,
                              void* d_out, int out_size, void* d_ws, size_t ws_size,
                              hipStream_t stream) {
  const float* patch = (const float*)d_in[0];
  const float* noun  = (const float*)d_in[1];
  const float* gimg  = (const float*)d_in[2];
  const float* gtxt  = (const float*)d_in[3];
  const float* lsc   = (const float*)d_in[4];
  const int*   idx   = (const int*)d_in[5];
  float* out = (float*)d_out;
  float* ws  = (float*)d_ws;

  // zero only the completion counter (ws is poisoned 0xAA each launch)
  hipMemsetAsync((char*)d_ws + (size_t)CNT_IDX * sizeof(float), 0, 4, stream);
  k_all<<<dim3(NBLK), dim3(512), 0, stream>>>(patch, noun, gimg, gtxt, lsc, idx, ws, out);
}

// Round 4
// 253.359 us; speedup vs baseline: 1.6622x; 1.6622x over previous
//
#include <hip/hip_runtime.h>
#include <hip/hip_bf16.h>
#include <math.h>

#define NB 64      // batch
#define NN 576     // patches
#define ND 512     // dim
#define NM 16      // nouns
#define QPB 9      // fine blocks per batch element (64 patches each)
#define NPB 64     // patches per fine block
#define NWF 8      // waves per fine block (D-split)
#define DPW 64     // d-range per wave
#define KPOS 5
#define TINV 14.2857142857142857f   // 1/0.07

#define WS_REC_OFF 4096             // after 64*64 scores
#define RECSZ 144                   // floats per fine-block record
#define CNT_IDX (WS_REC_OFF + NB * QPB * RECSZ)   // 87040
#define NBLK (NB * QPB + NB)        // 640

// LDS float offsets
#define L_NOUN 0                    // 16 x 512 noun slice for this b   (8192)
#define L_PART 8192                 // 4 x 16 x 64 partial sims         (4096)
#define L_SIM  12288                // 16 x 65 padded scaled sim        (1040)
#define L_TOT  13328                // 53,312 B -> up to 3 blocks/CU

#define FINF __builtin_inff()

// insert v into desc-sorted 5-list (constant indices only -> stays in VGPRs)
__device__ __forceinline__ void ins5(float (&a)[5], float v) {
  if (v > a[4]) {
    a[4] = v;
    if (a[4] > a[3]) { float x = a[4]; a[4] = a[3]; a[3] = x; }
    if (a[3] > a[2]) { float x = a[3]; a[3] = a[2]; a[2] = x; }
    if (a[2] > a[1]) { float x = a[2]; a[2] = a[1]; a[1] = x; }
    if (a[1] > a[0]) { float x = a[1]; a[1] = a[0]; a[0] = x; }
  }
}

// top-5 of union of two desc-sorted 5-lists, branch-free fixed-index rank merge
__device__ __forceinline__ void merge5(float (&a)[5], const float (&b)[5]) {
  float r[5];
#pragma unroll
  for (int k = 0; k < 5; ++k) {
    float best = -FINF;
#pragma unroll
    for (int i = 0; i <= k + 1; ++i) {
      const int j = k + 1 - i;
      const float av = (i == 0) ? FINF : a[i - 1];
      const float bv = (j == 0) ? FINF : b[j - 1];
      best = fmaxf(best, fminf(av, bv));
    }
    r[k] = best;
  }
#pragma unroll
  for (int k = 0; k < 5; ++k) a[k] = r[k];
}

__device__ __forceinline__ void merge5_shfl(float (&a)[5], int msk) {
  float o[5];
#pragma unroll
  for (int k = 0; k < 5; ++k) o[k] = __shfl_xor(a[k], msk, 64);
  merge5(a, o);
}

__global__ __launch_bounds__(512) void k_all(
    const float* __restrict__ patch, const float* __restrict__ noun,
    const float* __restrict__ gimg, const float* __restrict__ gtxt,
    const float* __restrict__ lscale, const int* __restrict__ idx,
    float* __restrict__ ws, float* __restrict__ out) {
  const int blk = blockIdx.x;
  const int t = threadIdx.x;
  const int lane = t & 63;

  __shared__ float L[L_TOT];
  __shared__ unsigned int winflag;

  if (blk < NB * QPB) {
    // ================= fine block: b, 64-patch slice =================
    const int b = blk / QPB;
    const int quad = blk - b * QPB;
    const int wv = __builtin_amdgcn_readfirstlane(t >> 6);  // 0..7, uniform

    // stage noun[b] (16x512 fp32 = 32 KB) into LDS, coalesced (issued first
    // so its vmcnt drains without waiting on the patch loads below)
    {
      const float4* ng = (const float4*)(noun + (size_t)b * NM * ND);
      float4* nl = (float4*)&L[L_NOUN];
#pragma unroll
      for (int k = 0; k < 4; ++k) nl[t + k * 512] = ng[t + k * 512];
    }

    // lane owns patch row (quad*64+lane); wave owns d-range [wv*64, wv*64+64)
    // 16 float4 = whole slice, issued up-front; in flight across the barrier
    const float4* prow = (const float4*)(patch +
        ((size_t)(b * NN + quad * NPB + lane)) * ND + wv * DPW);
    float4 stg[16];
#pragma unroll
    for (int k = 0; k < 16; ++k) stg[k] = prow[k];

    __syncthreads();   // noun LDS ready

    float acc[NM];
#pragma unroll
    for (int m = 0; m < NM; ++m) acc[m] = 0.f;

#pragma unroll
    for (int c = 0; c < 2; ++c) {       // two 32-float chunks of the d-range
#pragma unroll
      for (int m = 0; m < NM; ++m) {
        // broadcast ds_read_b128 (all lanes same address, imm offsets)
        const float4* nb4 = (const float4*)&L[L_NOUN + m * ND + wv * DPW + c * 32];
        float s0 = 0.f, s1 = 0.f;
#pragma unroll
        for (int k = 0; k < 8; ++k) {
          const float4 nv = nb4[k];
          const float4 pv = stg[c * 8 + k];
          s0 += pv.x * nv.x + pv.y * nv.y;
          s1 += pv.z * nv.z + pv.w * nv.w;
        }
        acc[m] += s0 + s1;
      }
    }

    // ---- two-round cross-wave reduction into 4 LDS buffers ----
    if (wv < 4) {
#pragma unroll
      for (int m = 0; m < NM; ++m) L[L_PART + wv * 1024 + m * 64 + lane] = acc[m];
    }
    __syncthreads();
    if (wv >= 4) {
#pragma unroll
      for (int m = 0; m < NM; ++m) L[L_PART + (wv - 4) * 1024 + m * 64 + lane] += acc[m];
    }
    __syncthreads();
    for (int i = t; i < 1024; i += 512) {
      const float s = L[L_PART + i] + L[L_PART + 1024 + i] +
                      L[L_PART + 2048 + i] + L[L_PART + 3072 + i];
      L[L_SIM + (i >> 6) * 65 + (i & 63)] = s * TINV;   // scaled sim
    }
    __syncthreads();

    const float* simL = &L[L_SIM];
    float* rec = ws + WS_REC_OFF + (size_t)blk * RECSZ;
    if (wv == 1) {
      // ---- mask partials: softplus sum + top5 of pooled/T over 64 patches ----
      float x = 0.f;
#pragma unroll
      for (int m = 0; m < NM; ++m) x += simL[m * 65 + lane];
      x *= (1.f / 16.f);
      float sxp = (x > 0.f) ? (x + log1pf(expf(-x))) : log1pf(expf(x));
      float t5[5] = {x, -FINF, -FINF, -FINF, -FINF};
#pragma unroll
      for (int msk = 1; msk < 64; msk <<= 1) {
        sxp += __shfl_xor(sxp, msk, 64);
        merge5_shfl(t5, msk);
      }
      if (lane == 0) {
        rec[128] = sxp;
#pragma unroll
        for (int k = 0; k < 5; ++k) rec[129 + k] = t5[k];
      }
    } else if (wv == 0) {
      // ---- per-noun row stats over 64 cols (16 rows x 4 segments) ----
      const int r_ = lane & 15;
      const int h = lane >> 4;
      const float* row = &simL[r_ * 65 + h * 16];
      float mx = -FINF;
#pragma unroll
      for (int k = 0; k < 16; ++k) mx = fmaxf(mx, row[k]);
      mx = fmaxf(mx, __shfl_xor(mx, 16, 64));
      mx = fmaxf(mx, __shfl_xor(mx, 32, 64));
      float se = 0.f;
      float r5[5] = {-FINF, -FINF, -FINF, -FINF, -FINF};
#pragma unroll
      for (int k = 0; k < 16; ++k) {
        const float v = row[k];
        se += expf(v - mx);
        ins5(r5, v);
      }
      se += __shfl_xor(se, 16, 64);
      se += __shfl_xor(se, 32, 64);
      merge5_shfl(r5, 16);
      merge5_shfl(r5, 32);
      if (h == 0) {
        float* rr = rec + r_ * 8;
        rr[0] = mx;
        rr[1] = se;
#pragma unroll
        for (int k = 0; k < 5; ++k) rr[2 + k] = r5[k];
      }
    }
  } else {
    // ================= score block: scores[i][j] = <img_i, txt_j> =================
    const int i = blk - NB * QPB;
    const int dq = t >> 6;   // 0..7 d-split
    const float4* ip = (const float4*)(gimg + (size_t)i * ND + dq * DPW);
    const float4* tp = (const float4*)(gtxt + (size_t)lane * ND + dq * DPW);
    float a = 0.f;
#pragma unroll
    for (int q = 0; q < DPW / 4; ++q) {
      const float4 x = ip[q];
      const float4 y = tp[q];
      a += x.x * y.x + x.y * y.y + x.z * y.z + x.w * y.w;
    }
    L[dq * 64 + lane] = a;
    __syncthreads();
    if (t < 64) {
      float s = 0.f;
#pragma unroll
      for (int w = 0; w < NWF; ++w) s += L[w * 64 + t];
      ws[i * 64 + t] = s;
    }
  }

  // ================= completion counter; last block runs the finale =================
  __syncthreads();
  __threadfence();                       // publish this block's ws writes device-wide
  if (t == 0) {
    const unsigned old = atomicAdd((unsigned int*)(ws + CNT_IDX), 1u);
    winflag = (old == NBLK - 1) ? 1u : 0u;
  }
  __syncthreads();
  if (!winflag) return;
  __threadfence();                       // acquire: see all other blocks' writes

  // ---- Part A: contrastive merge over (b, m) pairs; Part B: mask merge per b ----
  const float* recs = ws + WS_REC_OFF;
  float local = 0.f;
  for (int i = t; i < NB * NM; i += 512) {
    const int b = i >> 4, m = i & 15;
    const float* base = recs + (size_t)b * QPB * RECSZ + m * 8;
    float mx = -FINF;
#pragma unroll
    for (int q = 0; q < QPB; ++q) mx = fmaxf(mx, base[q * RECSZ]);
    float S = 0.f;
    float t5[5] = {-FINF, -FINF, -FINF, -FINF, -FINF};
#pragma unroll
    for (int q = 0; q < QPB; ++q) {
      S += base[q * RECSZ + 1] * expf(base[q * RECSZ] - mx);
#pragma unroll
      for (int k = 0; k < 5; ++k) ins5(t5, base[q * RECSZ + 2 + k]);
    }
    const float st = t5[0] + t5[1] + t5[2] + t5[3] + t5[4];
    local += (KPOS * (mx + logf(S)) - st) * (0.6f / (float)(NB * NM));
  }
  if (t < NB) {
    const float* base = recs + (size_t)t * QPB * RECSZ + 128;
    float sp = 0.f;
    float u5[5] = {-FINF, -FINF, -FINF, -FINF, -FINF};
#pragma unroll
    for (int q = 0; q < QPB; ++q) {
      sp += base[q * RECSZ];
#pragma unroll
      for (int k = 0; k < 5; ++k) ins5(u5, base[q * RECSZ + 1 + k]);
    }
    const float st = u5[0] + u5[1] + u5[2] + u5[3] + u5[4];
    local += (sp - st) * (0.4f / (float)(NB * NN));
  }
#pragma unroll
  for (int msk = 1; msk < 64; msk <<= 1) local += __shfl_xor(local, msk, 64);
  __syncthreads();                      // L free for reuse now
  if (lane == 0) L[t >> 6] = local;
  __syncthreads();
  if (t == 0) {
    float s = 0.f;
#pragma unroll
    for (int w = 0; w < NWF; ++w) s += L[w];
    out[2] = s;
  }
  __syncthreads();

  // ---- Part C: loss_c (CLIP bi-directional CE) + loss_t (triplet) ----
  float* S_ = &L[0];                     // 64 x 65 padded score tile
  for (int i = t; i < 4096; i += 512) S_[(i >> 6) * 65 + (i & 63)] = ws[i];
  __syncthreads();
  float* dgp = &L[4160];
  int* idl = (int*)&L[4224];
  if (t < 64) { dgp[t] = S_[t * 66]; idl[t] = idx[t]; }
  __syncthreads();
  if (t < 64) {                          // exactly wave 0
    const float sc = lscale[0];
    float mR = -FINF, mC = -FINF;
    for (int j = 0; j < 64; ++j) {
      mR = fmaxf(mR, sc * S_[t * 65 + j]);
      mC = fmaxf(mC, sc * S_[j * 65 + t]);
    }
    float seR = 0.f, seC = 0.f;
    for (int j = 0; j < 64; ++j) {
      seR += expf(sc * S_[t * 65 + j] - mR);
      seC += expf(sc * S_[j * 65 + t] - mC);
    }
    const float lseR = mR + logf(seR);
    const float lseC = mC + logf(seC);
    const int myid = idl[t];
    const float di = dgp[t];
    float ps = 0.f, trow = 0.f, tcol = 0.f, cs = 0.f, ci = 0.f;
    for (int j = 0; j < 64; ++j) {
      const float sv = S_[t * 65 + j];
      const float svT = S_[j * 65 + t];
      if (idl[j] == myid) {
        ps += 1.f;
        trow += sc * sv - lseR;
        tcol += sc * svT - lseC;
      }
      if (j != t) {
        cs += fmaxf(0.f, 0.1f + sv - di);
        ci += fmaxf(0.f, 0.1f + sv - dgp[j]);
      }
    }
    float vc = -(trow + tcol) / ps;
    float vt = cs + ci;
#pragma unroll
    for (int msk = 1; msk < 64; msk <<= 1) {
      vc += __shfl_xor(vc, msk, 64);
      vt += __shfl_xor(vt, msk, 64);
    }
    if (t == 0) {
      out[0] = vc * (0.5f / 64.f);
      out[1] = vt * 0.5f;
    }
  }
}

extern "C" void kernel_launch(void* const* d_in, const int* in_sizes, int n_in,
                              void* d_out, int out_size, void* d_ws, size_t ws_size,
                              hipStream_t stream) {
  const float* patch = (const float*)d_in[0];
  const float* noun  = (const float*)d_in[1];
  const float* gimg  = (const float*)d_in[2];
  const float* gtxt  = (const float*)d_in[3];
  const float* lsc   = (const float*)d_in[4];
  const int*   idx   = (const int*)d_in[5];
  float* out = (float*)d_out;
  float* ws  = (float*)d_ws;

  // zero only the completion counter (ws is poisoned 0xAA each launch)
  hipMemsetAsync((char*)d_ws + (size_t)CNT_IDX * sizeof(float), 0, 4, stream);
  k_all<<<dim3(NBLK), dim3(512), 0, stream>>>(patch, noun, gimg, gtxt, lsc, idx, ws, out);
}

// Round 5
// 250.933 us; speedup vs baseline: 1.6782x; 1.0097x over previous
//
#include <hip/hip_runtime.h>
#include <hip/hip_bf16.h>
#include <math.h>

#define NB 64      // batch
#define NN 576     // patches
#define ND 512     // dim
#define NM 16      // nouns
#define QPB 9      // fine blocks per batch element (64 patches each)
#define NPB 64     // patches per fine block
#define KPOS 5
#define TINV 14.2857142857142857f   // 1/0.07

#define WS_REC_OFF 4096             // after 64*64 scores
#define RECSZ 144                   // floats per fine-block record
#define CNT_IDX (WS_REC_OFF + NB * QPB * RECSZ)   // 87040
#define NBLK (NB * QPB + NB)        // 640

// LDS float offsets (32 KB total; noun area reused for reduce after FMA)
#define L_NOUN 0                    // 16 x 512 noun for this b (8192 floats)
#define L_PART 0                    // reuse: 4 x 16 x 64 partials (4096)
#define L_SIM  4096                 // 16 x 65 padded scaled sim (1040)
#define L_TOT  8192

#define FINF __builtin_inff()

// insert v into desc-sorted 5-list (constant indices only -> stays in VGPRs)
__device__ __forceinline__ void ins5(float (&a)[5], float v) {
  if (v > a[4]) {
    a[4] = v;
    if (a[4] > a[3]) { float x = a[4]; a[4] = a[3]; a[3] = x; }
    if (a[3] > a[2]) { float x = a[3]; a[3] = a[2]; a[2] = x; }
    if (a[2] > a[1]) { float x = a[2]; a[2] = a[1]; a[1] = x; }
    if (a[1] > a[0]) { float x = a[1]; a[1] = a[0]; a[0] = x; }
  }
}

// top-5 of union of two desc-sorted 5-lists, branch-free fixed-index rank merge
__device__ __forceinline__ void merge5(float (&a)[5], const float (&b)[5]) {
  float r[5];
#pragma unroll
  for (int k = 0; k < 5; ++k) {
    float best = -FINF;
#pragma unroll
    for (int i = 0; i <= k + 1; ++i) {
      const int j = k + 1 - i;
      const float av = (i == 0) ? FINF : a[i - 1];
      const float bv = (j == 0) ? FINF : b[j - 1];
      best = fmaxf(best, fminf(av, bv));
    }
    r[k] = best;
  }
#pragma unroll
  for (int k = 0; k < 5; ++k) a[k] = r[k];
}

__device__ __forceinline__ void merge5_shfl(float (&a)[5], int msk) {
  float o[5];
#pragma unroll
  for (int k = 0; k < 5; ++k) o[k] = __shfl_xor(a[k], msk, 64);
  merge5(a, o);
}

__global__ __launch_bounds__(256, 3) void k_all(
    const float* __restrict__ patch, const float* __restrict__ noun,
    const float* __restrict__ gimg, const float* __restrict__ gtxt,
    const float* __restrict__ lscale, const int* __restrict__ idx,
    float* __restrict__ ws, float* __restrict__ out) {
  const int blk = blockIdx.x;
  const int t = threadIdx.x;
  const int lane = t & 63;

  __shared__ float L[L_TOT];
  __shared__ unsigned int winflag;

  if (blk < NB * QPB) {
    // ================= fine block: b, 64-patch slice =================
    const int b = blk / QPB;
    const int quad = blk - b * QPB;
    const int wv = __builtin_amdgcn_readfirstlane(t >> 6);  // 0..3, uniform

    // lane owns patch row (quad*64+lane); wave owns d-range [wv*128, +128)
    const float* prow = patch + ((size_t)(b * NN + quad * NPB + lane)) * ND + wv * 128;

    float4 A[8], B[8], C[8];
    // preload chunks 0 and 1 (loads stay in flight across the staging barrier)
#pragma unroll
    for (int k = 0; k < 8; ++k) A[k] = ((const float4*)prow)[k];
#pragma unroll
    for (int k = 0; k < 8; ++k) B[k] = ((const float4*)(prow + 32))[k];

    // stage noun[b] (16x512 fp32 = 32 KB) into LDS, coalesced
    {
      const float4* ng = (const float4*)(noun + (size_t)b * NM * ND);
      float4* nl = (float4*)&L[L_NOUN];
#pragma unroll
      for (int k = 0; k < 8; ++k) nl[t + k * 256] = ng[t + k * 256];
    }
    __syncthreads();   // noun LDS ready

    float acc[NM];
#pragma unroll
    for (int m = 0; m < NM; ++m) acc[m] = 0.f;

    // one chunk = 32 floats of this wave's 128-d range; noun read broadcast
#define FMA_CHUNK(P, c)                                                      \
    {                                                                        \
      const float* nL = &L[L_NOUN + wv * 128 + (c) * 32];                    \
      _Pragma("unroll")                                                      \
      for (int m = 0; m < NM; ++m) {                                         \
        const float4* n4 = (const float4*)(nL + m * ND);                     \
        float s0 = 0.f, s1 = 0.f;                                            \
        _Pragma("unroll")                                                    \
        for (int k = 0; k < 8; ++k) {                                        \
          const float4 nv = n4[k];                                           \
          const float4 pv = P[k];                                            \
          s0 += pv.x * nv.x + pv.y * nv.y;                                   \
          s1 += pv.z * nv.z + pv.w * nv.w;                                   \
        }                                                                    \
        acc[m] += s0 + s1;                                                   \
      }                                                                      \
    }

#pragma unroll
    for (int k = 0; k < 8; ++k) C[k] = ((const float4*)(prow + 64))[k];  // c2
    FMA_CHUNK(A, 0)
#pragma unroll
    for (int k = 0; k < 8; ++k) A[k] = ((const float4*)(prow + 96))[k]; // c3
    FMA_CHUNK(B, 1)
    FMA_CHUNK(C, 2)
    FMA_CHUNK(A, 3)
#undef FMA_CHUNK

    // ---- cross-wave reduction (reuse noun LDS area; all reads done) ----
    __syncthreads();
#pragma unroll
    for (int m = 0; m < NM; ++m) L[L_PART + wv * 1024 + m * 64 + lane] = acc[m];
    __syncthreads();
    for (int i = t; i < 1024; i += 256) {
      const float s = L[L_PART + i] + L[L_PART + 1024 + i] +
                      L[L_PART + 2048 + i] + L[L_PART + 3072 + i];
      L[L_SIM + (i >> 6) * 65 + (i & 63)] = s * TINV;   // scaled sim
    }
    __syncthreads();

    const float* simL = &L[L_SIM];
    float* rec = ws + WS_REC_OFF + (size_t)blk * RECSZ;
    if (wv == 1) {
      // ---- mask partials: softplus sum + top5 of pooled/T over 64 patches ----
      float x = 0.f;
#pragma unroll
      for (int m = 0; m < NM; ++m) x += simL[m * 65 + lane];
      x *= (1.f / 16.f);
      float sxp = (x > 0.f) ? (x + log1pf(expf(-x))) : log1pf(expf(x));
      float t5[5] = {x, -FINF, -FINF, -FINF, -FINF};
#pragma unroll
      for (int msk = 1; msk < 64; msk <<= 1) {
        sxp += __shfl_xor(sxp, msk, 64);
        merge5_shfl(t5, msk);
      }
      if (lane == 0) {
        rec[128] = sxp;
#pragma unroll
        for (int k = 0; k < 5; ++k) rec[129 + k] = t5[k];
      }
    } else if (wv == 0) {
      // ---- per-noun row stats over 64 cols (16 rows x 4 segments) ----
      const int r_ = lane & 15;
      const int h = lane >> 4;
      const float* row = &simL[r_ * 65 + h * 16];
      float mx = -FINF;
#pragma unroll
      for (int k = 0; k < 16; ++k) mx = fmaxf(mx, row[k]);
      mx = fmaxf(mx, __shfl_xor(mx, 16, 64));
      mx = fmaxf(mx, __shfl_xor(mx, 32, 64));
      float se = 0.f;
      float r5[5] = {-FINF, -FINF, -FINF, -FINF, -FINF};
#pragma unroll
      for (int k = 0; k < 16; ++k) {
        const float v = row[k];
        se += expf(v - mx);
        ins5(r5, v);
      }
      se += __shfl_xor(se, 16, 64);
      se += __shfl_xor(se, 32, 64);
      merge5_shfl(r5, 16);
      merge5_shfl(r5, 32);
      if (h == 0) {
        float* rr = rec + r_ * 8;
        rr[0] = mx;
        rr[1] = se;
#pragma unroll
        for (int k = 0; k < 5; ++k) rr[2 + k] = r5[k];
      }
    }
  } else {
    // ================= score block: scores[i][j] = <img_i, txt_j> =================
    const int i = blk - NB * QPB;
    const int dq = t >> 6;   // 0..3 d-split (128 floats each)
    const float4* ip = (const float4*)(gimg + (size_t)i * ND + dq * 128);
    const float4* tp = (const float4*)(gtxt + (size_t)lane * ND + dq * 128);
    float a = 0.f;
#pragma unroll
    for (int q = 0; q < 32; ++q) {
      const float4 x = ip[q];
      const float4 y = tp[q];
      a += x.x * y.x + x.y * y.y + x.z * y.z + x.w * y.w;
    }
    L[dq * 64 + lane] = a;
    __syncthreads();
    if (t < 64) ws[i * 64 + t] = L[t] + L[64 + t] + L[128 + t] + L[192 + t];
  }

  // ================= completion counter; last block runs the finale =================
  __syncthreads();
  __threadfence();                       // publish this block's ws writes device-wide
  if (t == 0) {
    const unsigned old = atomicAdd((unsigned int*)(ws + CNT_IDX), 1u);
    winflag = (old == NBLK - 1) ? 1u : 0u;
  }
  __syncthreads();
  if (!winflag) return;
  __threadfence();                       // acquire: see all other blocks' writes

  // ---- Part A: contrastive merge over (b, m) pairs; Part B: mask merge per b ----
  const float* recs = ws + WS_REC_OFF;
  float local = 0.f;
  for (int i = t; i < NB * NM; i += 256) {
    const int b = i >> 4, m = i & 15;
    const float* base = recs + (size_t)b * QPB * RECSZ + m * 8;
    float mx = -FINF;
#pragma unroll
    for (int q = 0; q < QPB; ++q) mx = fmaxf(mx, base[q * RECSZ]);
    float S = 0.f;
    float t5[5] = {-FINF, -FINF, -FINF, -FINF, -FINF};
#pragma unroll
    for (int q = 0; q < QPB; ++q) {
      S += base[q * RECSZ + 1] * expf(base[q * RECSZ] - mx);
#pragma unroll
      for (int k = 0; k < 5; ++k) ins5(t5, base[q * RECSZ + 2 + k]);
    }
    const float st = t5[0] + t5[1] + t5[2] + t5[3] + t5[4];
    local += (KPOS * (mx + logf(S)) - st) * (0.6f / (float)(NB * NM));
  }
  if (t < NB) {
    const float* base = recs + (size_t)t * QPB * RECSZ + 128;
    float sp = 0.f;
    float u5[5] = {-FINF, -FINF, -FINF, -FINF, -FINF};
#pragma unroll
    for (int q = 0; q < QPB; ++q) {
      sp += base[q * RECSZ];
#pragma unroll
      for (int k = 0; k < 5; ++k) ins5(u5, base[q * RECSZ + 1 + k]);
    }
    const float st = u5[0] + u5[1] + u5[2] + u5[3] + u5[4];
    local += (sp - st) * (0.4f / (float)(NB * NN));
  }
#pragma unroll
  for (int msk = 1; msk < 64; msk <<= 1) local += __shfl_xor(local, msk, 64);
  __syncthreads();                      // L free for reuse now
  if (lane == 0) L[t >> 6] = local;
  __syncthreads();
  if (t == 0) out[2] = L[0] + L[1] + L[2] + L[3];
  __syncthreads();

  // ---- Part C: loss_c (CLIP bi-directional CE) + loss_t (triplet) ----
  float* S_ = &L[0];                     // 64 x 65 padded score tile
  for (int i = t; i < 4096; i += 256) S_[(i >> 6) * 65 + (i & 63)] = ws[i];
  __syncthreads();
  float* dgp = &L[4160];
  int* idl = (int*)&L[4224];
  if (t < 64) { dgp[t] = S_[t * 66]; idl[t] = idx[t]; }
  __syncthreads();
  if (t < 64) {                          // exactly wave 0
    const float sc = lscale[0];
    float mR = -FINF, mC = -FINF;
    for (int j = 0; j < 64; ++j) {
      mR = fmaxf(mR, sc * S_[t * 65 + j]);
      mC = fmaxf(mC, sc * S_[j * 65 + t]);
    }
    float seR = 0.f, seC = 0.f;
    for (int j = 0; j < 64; ++j) {
      seR += expf(sc * S_[t * 65 + j] - mR);
      seC += expf(sc * S_[j * 65 + t] - mC);
    }
    const float lseR = mR + logf(seR);
    const float lseC = mC + logf(seC);
    const int myid = idl[t];
    const float di = dgp[t];
    float ps = 0.f, trow = 0.f, tcol = 0.f, cs = 0.f, ci = 0.f;
    for (int j = 0; j < 64; ++j) {
      const float sv = S_[t * 65 + j];
      const float svT = S_[j * 65 + t];
      if (idl[j] == myid) {
        ps += 1.f;
        trow += sc * sv - lseR;
        tcol += sc * svT - lseC;
      }
      if (j != t) {
        cs += fmaxf(0.f, 0.1f + sv - di);
        ci += fmaxf(0.f, 0.1f + sv - dgp[j]);
      }
    }
    float vc = -(trow + tcol) / ps;
    float vt = cs + ci;
#pragma unroll
    for (int msk = 1; msk < 64; msk <<= 1) {
      vc += __shfl_xor(vc, msk, 64);
      vt += __shfl_xor(vt, msk, 64);
    }
    if (t == 0) {
      out[0] = vc * (0.5f / 64.f);
      out[1] = vt * 0.5f;
    }
  }
}

extern "C" void kernel_launch(void* const* d_in, const int* in_sizes, int n_in,
                              void* d_out, int out_size, void* d_ws, size_t ws_size,
                              hipStream_t stream) {
  const float* patch = (const float*)d_in[0];
  const float* noun  = (const float*)d_in[1];
  const float* gimg  = (const float*)d_in[2];
  const float* gtxt  = (const float*)d_in[3];
  const float* lsc   = (const float*)d_in[4];
  const int*   idx   = (const int*)d_in[5];
  float* out = (float*)d_out;
  float* ws  = (float*)d_ws;

  // zero only the completion counter (ws is poisoned 0xAA each launch)
  hipMemsetAsync((char*)d_ws + (size_t)CNT_IDX * sizeof(float), 0, 4, stream);
  k_all<<<dim3(NBLK), dim3(256), 0, stream>>>(patch, noun, gimg, gtxt, lsc, idx, ws, out);
}

// Round 6
// 149.539 us; speedup vs baseline: 2.8161x; 1.6780x over previous
//
#include <hip/hip_runtime.h>
#include <hip/hip_bf16.h>
#include <math.h>

#define NB 64      // batch
#define NN 576     // patches
#define ND 512     // dim
#define NM 16      // nouns
#define QPB 9      // quads per batch element (64 patches each)
#define KPOS 5
#define TINV 14.2857142857142857f   // 1/0.07

#define NFINE (NB * QPB * 2)        // 1152 fine blocks (x2 d-halves)
#define NBLK1 (NFINE + NB)          // 1216
#define WS_SIM 4096                 // sim partial tiles after 64x64 scores
#define LSTR 33                     // padded LDS row stride -> conflict-free b32

#define FINF __builtin_inff()

// insert v into desc-sorted 5-list (constant indices only -> stays in VGPRs)
__device__ __forceinline__ void ins5(float (&a)[5], float v) {
  if (v > a[4]) {
    a[4] = v;
    if (a[4] > a[3]) { float x = a[4]; a[4] = a[3]; a[3] = x; }
    if (a[3] > a[2]) { float x = a[3]; a[3] = a[2]; a[2] = x; }
    if (a[2] > a[1]) { float x = a[2]; a[2] = a[1]; a[1] = x; }
    if (a[1] > a[0]) { float x = a[1]; a[1] = a[0]; a[0] = x; }
  }
}

// top-5 of union of two desc-sorted 5-lists, branch-free fixed-index rank merge
__device__ __forceinline__ void merge5(float (&a)[5], const float (&b)[5]) {
  float r[5];
#pragma unroll
  for (int k = 0; k < 5; ++k) {
    float best = -FINF;
#pragma unroll
    for (int i = 0; i <= k + 1; ++i) {
      const int j = k + 1 - i;
      const float av = (i == 0) ? FINF : a[i - 1];
      const float bv = (j == 0) ? FINF : b[j - 1];
      best = fmaxf(best, fminf(av, bv));
    }
    r[k] = best;
  }
#pragma unroll
  for (int k = 0; k < 5; ++k) a[k] = r[k];
}

__device__ __forceinline__ void merge5_shfl(float (&a)[5], int msk) {
  float o[5];
#pragma unroll
  for (int k = 0; k < 5; ++k) o[k] = __shfl_xor(a[k], msk, 64);
  merge5(a, o);
}

// ============ kernel 1: sim partial tiles + global scores ============
// fine block (b, quad, half): 4 waves x 64-d subranges of this 256-d half;
// lane owns one patch column. Patch staged global->LDS->reg per 32-d chunk
// (the LDS round-trip pins loads before the barrier = enforced pipelining,
// proven in R2; direct per-lane loads get sunk by the compiler = R4/R5 loss).
// Noun read wave-uniform -> s_load, feeds v_fma from SGPRs (no LDS).
__global__ __launch_bounds__(256) void k_sim(
    const float* __restrict__ patch, const float* __restrict__ noun,
    const float* __restrict__ gimg, const float* __restrict__ gtxt,
    float* __restrict__ ws) {
  const int blk = blockIdx.x;
  const int t = threadIdx.x;
  const int lane = t & 63;

  __shared__ float L[4 * 64 * LSTR];   // 8448 floats = 33.8 KB (reused for reduce)

  if (blk < NFINE) {
    const int bq = blk >> 1, h = blk & 1;
    const int b = bq / QPB, quad = bq - b * QPB;
    const int wv = __builtin_amdgcn_readfirstlane(t >> 6);  // 0..3, uniform
    const int d0 = h * 256 + wv * 64;

    const float* pbase = patch + ((size_t)(b * NN + quad * 64)) * ND + d0;
    const float* nbase = noun + (size_t)b * NM * ND + d0;
    float* WP = &L[wv * (64 * LSTR)];   // wave-private staging buffer

    const int sp = lane >> 3;   // staging patch-row (within group of 8)
    const int sf = lane & 7;    // staging float4 index

    float acc[NM];
#pragma unroll
    for (int m = 0; m < NM; ++m) acc[m] = 0.f;

    float4 stg[8];
#pragma unroll
    for (int r = 0; r < 8; ++r)
      stg[r] = *(const float4*)(pbase + (size_t)(8 * r + sp) * ND + sf * 4);

#pragma unroll
    for (int c = 0; c < 2; ++c) {       // two 32-float chunks of the 64-d range
      __syncthreads();
#pragma unroll
      for (int r = 0; r < 8; ++r) {
        float* dst = &WP[(8 * r + sp) * LSTR + sf * 4];
        dst[0] = stg[r].x; dst[1] = stg[r].y; dst[2] = stg[r].z; dst[3] = stg[r].w;
      }
      __syncthreads();
      if (c == 0) {
#pragma unroll
        for (int r = 0; r < 8; ++r)
          stg[r] = *(const float4*)(pbase + 32 + (size_t)(8 * r + sp) * ND + sf * 4);
      }
      float pf[32];
#pragma unroll
      for (int d = 0; d < 32; ++d) pf[d] = WP[lane * LSTR + d];  // conflict-free b32
      const float* nc = nbase + c * 32;   // wave-uniform -> s_load
#pragma unroll 4
      for (int m = 0; m < NM; ++m) {
        const float* np_ = nc + m * ND;
        float s0 = 0.f, s1 = 0.f;
#pragma unroll
        for (int d = 0; d < 32; d += 2) {
          s0 += pf[d] * np_[d];
          s1 += pf[d + 1] * np_[d + 1];
        }
        acc[m] += s0 + s1;
      }
    }

    // cross-wave reduce (reuse staging LDS) and write the 16x64 partial tile
    __syncthreads();
#pragma unroll
    for (int m = 0; m < NM; ++m) L[wv * 1024 + m * 64 + lane] = acc[m];
    __syncthreads();
    float* dst = ws + WS_SIM + (size_t)blk * 1024;
    for (int i = t; i < 1024; i += 256)
      dst[i] = L[i] + L[1024 + i] + L[2048 + i] + L[3072 + i];
  } else {
    // score block: scores[i][j] = <img_i, txt_j>
    const int i = blk - NFINE;
    const int dq = t >> 6;   // 0..3 d-split (128 floats each)
    const float4* ip = (const float4*)(gimg + (size_t)i * ND + dq * 128);
    const float4* tp = (const float4*)(gtxt + (size_t)lane * ND + dq * 128);
    float a = 0.f;
#pragma unroll
    for (int q = 0; q < 32; ++q) {
      const float4 x = ip[q];
      const float4 y = tp[q];
      a += x.x * y.x + x.y * y.y + x.z * y.z + x.w * y.w;
    }
    L[dq * 64 + lane] = a;
    __syncthreads();
    if (t < 64) ws[i * 64 + t] = L[t] + L[64 + t] + L[128 + t] + L[192 + t];
  }
}

// ============ kernel 2: all losses ============
__global__ __launch_bounds__(256) void k_loss(
    const float* __restrict__ ws, const float* __restrict__ lscale,
    const int* __restrict__ idx, float* __restrict__ out) {
  const int blk = blockIdx.x;
  const int t = threadIdx.x;
  const int lane = t & 63;
  const int w = t >> 6;

  __shared__ float S[NM * 577 + 64];   // 37.2 KB; tail used for reductions

  if (blk < NB) {
    // ---- stage full scaled sim[16][576] for batch b, summing the 2 d-halves ----
    const int b = blk;
#pragma unroll
    for (int q = 0; q < QPB; ++q) {
      const float4* t0 = (const float4*)(ws + WS_SIM + ((size_t)(b * QPB + q) * 2 + 0) * 1024);
      const float4* t1 = (const float4*)(ws + WS_SIM + ((size_t)(b * QPB + q) * 2 + 1) * 1024);
      const float4 a = t0[t];
      const float4 c = t1[t];
      const int i0 = 4 * t;            // element index in 16x64 tile
      const int m = i0 >> 6, p = i0 & 63;
      float* dst = &S[m * 577 + q * 64 + p];
      dst[0] = (a.x + c.x) * TINV;
      dst[1] = (a.y + c.y) * TINV;
      dst[2] = (a.z + c.z) * TINV;
      dst[3] = (a.w + c.w) * TINV;
    }
    __syncthreads();

    // ---- per-noun contrastive: wave w handles m = 4w..4w+3 over 576 cols ----
    float cpart = 0.f;
#pragma unroll
    for (int mi = 0; mi < 4; ++mi) {
      const int m = w * 4 + mi;
      const float* row = &S[m * 577];
      float mx = -FINF;
#pragma unroll
      for (int k = 0; k < 9; ++k) mx = fmaxf(mx, row[lane + 64 * k]);
#pragma unroll
      for (int msk = 1; msk < 64; msk <<= 1) mx = fmaxf(mx, __shfl_xor(mx, msk, 64));
      float se = 0.f;
      float t5[5] = {-FINF, -FINF, -FINF, -FINF, -FINF};
#pragma unroll
      for (int k = 0; k < 9; ++k) {
        const float v = row[lane + 64 * k];
        se += expf(v - mx);
        ins5(t5, v);
      }
#pragma unroll
      for (int msk = 1; msk < 64; msk <<= 1) {
        se += __shfl_xor(se, msk, 64);
        merge5_shfl(t5, msk);
      }
      if (lane == 0) {
        const float st = t5[0] + t5[1] + t5[2] + t5[3] + t5[4];
        cpart += (KPOS * (mx + logf(se)) - st) * (0.6f / (float)(NB * NM));
      }
    }

    // ---- mask loss: pooled/T = column mean; softplus sum + top5 ----
    float sxp = 0.f;
    float u5[5] = {-FINF, -FINF, -FINF, -FINF, -FINF};
#pragma unroll
    for (int rep = 0; rep < 3; ++rep) {
      const int n = t + rep * 256;
      if (n < NN) {
        float cs = 0.f;
#pragma unroll
        for (int m = 0; m < NM; ++m) cs += S[m * 577 + n];
        const float x = cs * (1.f / 16.f);
        sxp += (x > 0.f) ? (x + log1pf(expf(-x))) : log1pf(expf(x));
        ins5(u5, x);
      }
    }
#pragma unroll
    for (int msk = 1; msk < 64; msk <<= 1) {
      sxp += __shfl_xor(sxp, msk, 64);
      merge5_shfl(u5, msk);
    }
    // per-wave partials -> LDS tail -> thread 0
    float* R = &S[NM * 577];
    if (lane == 0) {
      R[w] = cpart;
      R[8 + w] = sxp;
#pragma unroll
      for (int k = 0; k < 5; ++k) R[16 + w * 5 + k] = u5[k];
    }
    __syncthreads();
    if (t == 0) {
      float tot = R[0] + R[1] + R[2] + R[3];
      float sp = R[8] + R[9] + R[10] + R[11];
      float f5[5] = {R[16], R[17], R[18], R[19], R[20]};
#pragma unroll
      for (int ww = 1; ww < 4; ++ww) {
        float o[5] = {R[16 + ww * 5], R[17 + ww * 5], R[18 + ww * 5],
                      R[19 + ww * 5], R[20 + ww * 5]};
        merge5(f5, o);
      }
      const float st = f5[0] + f5[1] + f5[2] + f5[3] + f5[4];
      tot += (sp - st) * (0.4f / (float)(NB * NN));
      atomicAdd(out + 2, tot);
    }
    return;
  }

  // ---- block 64: loss_c (CLIP bi-directional CE) + loss_t (triplet) ----
  float* S_ = &S[0];                     // 64 x 65 padded score tile
  for (int i = t; i < 4096; i += 256) S_[(i >> 6) * 65 + (i & 63)] = ws[i];
  __syncthreads();
  float* dgp = &S[4160];
  int* idl = (int*)&S[4224];
  if (t < 64) { dgp[t] = S_[t * 66]; idl[t] = idx[t]; }
  __syncthreads();
  if (t < 64) {                          // exactly wave 0
    const float sc = lscale[0];
    float mR = -FINF, mC = -FINF;
    for (int j = 0; j < 64; ++j) {
      mR = fmaxf(mR, sc * S_[t * 65 + j]);
      mC = fmaxf(mC, sc * S_[j * 65 + t]);
    }
    float seR = 0.f, seC = 0.f;
    for (int j = 0; j < 64; ++j) {
      seR += expf(sc * S_[t * 65 + j] - mR);
      seC += expf(sc * S_[j * 65 + t] - mC);
    }
    const float lseR = mR + logf(seR);
    const float lseC = mC + logf(seC);
    const int myid = idl[t];
    const float di = dgp[t];
    float ps = 0.f, trow = 0.f, tcol = 0.f, cs = 0.f, ci = 0.f;
    for (int j = 0; j < 64; ++j) {
      const float sv = S_[t * 65 + j];
      const float svT = S_[j * 65 + t];
      if (idl[j] == myid) {
        ps += 1.f;
        trow += sc * sv - lseR;
        tcol += sc * svT - lseC;
      }
      if (j != t) {
        cs += fmaxf(0.f, 0.1f + sv - di);
        ci += fmaxf(0.f, 0.1f + sv - dgp[j]);
      }
    }
    float vc = -(trow + tcol) / ps;
    float vt = cs + ci;
#pragma unroll
    for (int msk = 1; msk < 64; msk <<= 1) {
      vc += __shfl_xor(vc, msk, 64);
      vt += __shfl_xor(vt, msk, 64);
    }
    if (t == 0) {
      out[0] = vc * (0.5f / 64.f);
      out[1] = vt * 0.5f;
    }
  }
}

extern "C" void kernel_launch(void* const* d_in, const int* in_sizes, int n_in,
                              void* d_out, int out_size, void* d_ws, size_t ws_size,
                              hipStream_t stream) {
  const float* patch = (const float*)d_in[0];
  const float* noun  = (const float*)d_in[1];
  const float* gimg  = (const float*)d_in[2];
  const float* gtxt  = (const float*)d_in[3];
  const float* lsc   = (const float*)d_in[4];
  const int*   idx   = (const int*)d_in[5];
  float* out = (float*)d_out;
  float* ws  = (float*)d_ws;

  // out[2] accumulated via atomicAdd across k_loss blocks; harness poisons d_out
  hipMemsetAsync(d_out, 0, 3 * sizeof(float), stream);
  k_sim<<<dim3(NBLK1), dim3(256), 0, stream>>>(patch, noun, gimg, gtxt, ws);
  k_loss<<<dim3(NB + 1), dim3(256), 0, stream>>>(ws, lsc, idx, out);
}

// Round 7
// 140.570 us; speedup vs baseline: 2.9958x; 1.0638x over previous
//
#include <hip/hip_runtime.h>
#include <hip/hip_bf16.h>
#include <math.h>

#define NB 64      // batch
#define NN 576     // patches
#define ND 512     // dim
#define NM 16      // nouns
#define QPB 9      // quads per batch element (64 patches each)
#define KPOS 5
#define TINV 14.2857142857142857f   // 1/0.07

#define NFINE (NB * QPB)            // 576 fine blocks
#define NBLK1 (NFINE + NB)          // 640
#define WS_SIM 4096                 // sim tiles after 64x64 scores

#define FINF __builtin_inff()

typedef __attribute__((ext_vector_type(8))) short short8;   // 8 bf16 (4 VGPRs)
typedef __attribute__((ext_vector_type(4))) float floatx4;  // MFMA C/D

// fp32 -> bf16 round-to-nearest-even (bit twiddle; matches HW semantics)
__device__ __forceinline__ short f2bf(float f) {
  unsigned u = __float_as_uint(f);
  u += 0x7FFFu + ((u >> 16) & 1u);
  return (short)(u >> 16);
}

__device__ __forceinline__ short8 pack8(const float4 a, const float4 b) {
  short8 r;
  r[0] = f2bf(a.x); r[1] = f2bf(a.y); r[2] = f2bf(a.z); r[3] = f2bf(a.w);
  r[4] = f2bf(b.x); r[5] = f2bf(b.y); r[6] = f2bf(b.z); r[7] = f2bf(b.w);
  return r;
}

// insert v into desc-sorted 5-list (constant indices only -> stays in VGPRs)
__device__ __forceinline__ void ins5(float (&a)[5], float v) {
  if (v > a[4]) {
    a[4] = v;
    if (a[4] > a[3]) { float x = a[4]; a[4] = a[3]; a[3] = x; }
    if (a[3] > a[2]) { float x = a[3]; a[3] = a[2]; a[2] = x; }
    if (a[2] > a[1]) { float x = a[2]; a[2] = a[1]; a[1] = x; }
    if (a[1] > a[0]) { float x = a[1]; a[1] = a[0]; a[0] = x; }
  }
}

// top-5 of union of two desc-sorted 5-lists, branch-free fixed-index rank merge
__device__ __forceinline__ void merge5(float (&a)[5], const float (&b)[5]) {
  float r[5];
#pragma unroll
  for (int k = 0; k < 5; ++k) {
    float best = -FINF;
#pragma unroll
    for (int i = 0; i <= k + 1; ++i) {
      const int j = k + 1 - i;
      const float av = (i == 0) ? FINF : a[i - 1];
      const float bv = (j == 0) ? FINF : b[j - 1];
      best = fmaxf(best, fminf(av, bv));
    }
    r[k] = best;
  }
#pragma unroll
  for (int k = 0; k < 5; ++k) a[k] = r[k];
}

__device__ __forceinline__ void merge5_shfl(float (&a)[5], int msk) {
  float o[5];
#pragma unroll
  for (int k = 0; k < 5; ++k) o[k] = __shfl_xor(a[k], msk, 64);
  merge5(a, o);
}

// ============ kernel 1: sim tiles (bf16 MFMA) + global scores ============
// fine block (b, quad): 4 waves; wave w computes the full-K 16-noun x 16-patch
// C-tile for patches quad*64 + w*16 .. +15. Fragments loaded DIRECTLY from
// global (each value used once -> nothing for the compiler to sink/remat;
// no LDS, no barriers, no s_load chains). A=noun, B=patch^T.
__global__ __launch_bounds__(256) void k_sim(
    const float* __restrict__ patch, const float* __restrict__ noun,
    const float* __restrict__ gimg, const float* __restrict__ gtxt,
    float* __restrict__ ws) {
  const int blk = blockIdx.x;
  const int t = threadIdx.x;
  const int lane = t & 63;

  __shared__ float L[256];   // score path only

  if (blk < NFINE) {
    const int b = blk / QPB, quad = blk - b * QPB;
    const int w = t >> 6;
    const int nidx = lane & 15;          // A: noun row m / B: patch col n
    const int k0 = (lane >> 4) * 8;      // k-offset within 32-wide kstep

    // lane's source rows (A: noun m=nidx; B: patch p = quad*64 + w*16 + nidx)
    const float* nrow = noun + ((size_t)b * NM + nidx) * ND + k0;
    const float* prow = patch + ((size_t)(b * NN + quad * 64 + w * 16 + nidx)) * ND + k0;

    floatx4 acc = {0.f, 0.f, 0.f, 0.f};
#pragma unroll
    for (int ks = 0; ks < 16; ++ks) {
      const int o = ks * 32;
      const float4 a0 = *(const float4*)(nrow + o);
      const float4 a1 = *(const float4*)(nrow + o + 4);
      const float4 p0 = *(const float4*)(prow + o);
      const float4 p1 = *(const float4*)(prow + o + 4);
      const short8 af = pack8(a0, a1);
      const short8 bf = pack8(p0, p1);
      acc = __builtin_amdgcn_mfma_f32_16x16x32_bf16(af, bf, acc, 0, 0, 0);
    }

    // C/D layout: col(=patch)=lane&15, row(=noun)=(lane>>4)*4+r  [m89-verified]
    float* dst = ws + WS_SIM + (size_t)blk * 1024;
    const int mrow = (lane >> 4) * 4;
    const int pcol = w * 16 + nidx;
#pragma unroll
    for (int r = 0; r < 4; ++r) dst[(mrow + r) * 64 + pcol] = acc[r];
  } else {
    // score block: scores[i][j] = <img_i, txt_j>
    const int i = blk - NFINE;
    const int dq = t >> 6;   // 0..3 d-split (128 floats each)
    const float4* ip = (const float4*)(gimg + (size_t)i * ND + dq * 128);
    const float4* tp = (const float4*)(gtxt + (size_t)lane * ND + dq * 128);
    float a = 0.f;
#pragma unroll
    for (int q = 0; q < 32; ++q) {
      const float4 x = ip[q];
      const float4 y = tp[q];
      a += x.x * y.x + x.y * y.y + x.z * y.z + x.w * y.w;
    }
    L[dq * 64 + lane] = a;
    __syncthreads();
    if (t < 64) ws[i * 64 + t] = L[t] + L[64 + t] + L[128 + t] + L[192 + t];
  }
}

// ============ kernel 2: all losses ============
__global__ __launch_bounds__(256) void k_loss(
    const float* __restrict__ ws, const float* __restrict__ lscale,
    const int* __restrict__ idx, float* __restrict__ out) {
  const int blk = blockIdx.x;
  const int t = threadIdx.x;
  const int lane = t & 63;
  const int w = t >> 6;

  __shared__ float S[NM * 577 + 64];   // 37.2 KB; tail used for reductions

  if (blk < NB) {
    // ---- stage full scaled sim[16][576] for batch b from the 9 quad tiles ----
    const int b = blk;
#pragma unroll
    for (int q = 0; q < QPB; ++q) {
      const float4* t0 = (const float4*)(ws + WS_SIM + (size_t)(b * QPB + q) * 1024);
      const float4 a = t0[t];
      const int i0 = 4 * t;            // element index in 16x64 tile
      const int m = i0 >> 6, p = i0 & 63;
      float* dst = &S[m * 577 + q * 64 + p];
      dst[0] = a.x * TINV;
      dst[1] = a.y * TINV;
      dst[2] = a.z * TINV;
      dst[3] = a.w * TINV;
    }
    __syncthreads();

    // ---- per-noun contrastive: wave w handles m = 4w..4w+3 over 576 cols ----
    float cpart = 0.f;
#pragma unroll
    for (int mi = 0; mi < 4; ++mi) {
      const int m = w * 4 + mi;
      const float* row = &S[m * 577];
      float mx = -FINF;
#pragma unroll
      for (int k = 0; k < 9; ++k) mx = fmaxf(mx, row[lane + 64 * k]);
#pragma unroll
      for (int msk = 1; msk < 64; msk <<= 1) mx = fmaxf(mx, __shfl_xor(mx, msk, 64));
      float se = 0.f;
      float t5[5] = {-FINF, -FINF, -FINF, -FINF, -FINF};
#pragma unroll
      for (int k = 0; k < 9; ++k) {
        const float v = row[lane + 64 * k];
        se += expf(v - mx);
        ins5(t5, v);
      }
#pragma unroll
      for (int msk = 1; msk < 64; msk <<= 1) {
        se += __shfl_xor(se, msk, 64);
        merge5_shfl(t5, msk);
      }
      if (lane == 0) {
        const float st = t5[0] + t5[1] + t5[2] + t5[3] + t5[4];
        cpart += (KPOS * (mx + logf(se)) - st) * (0.6f / (float)(NB * NM));
      }
    }

    // ---- mask loss: pooled/T = column mean; softplus sum + top5 ----
    float sxp = 0.f;
    float u5[5] = {-FINF, -FINF, -FINF, -FINF, -FINF};
#pragma unroll
    for (int rep = 0; rep < 3; ++rep) {
      const int n = t + rep * 256;
      if (n < NN) {
        float cs = 0.f;
#pragma unroll
        for (int m = 0; m < NM; ++m) cs += S[m * 577 + n];
        const float x = cs * (1.f / 16.f);
        sxp += (x > 0.f) ? (x + log1pf(expf(-x))) : log1pf(expf(x));
        ins5(u5, x);
      }
    }
#pragma unroll
    for (int msk = 1; msk < 64; msk <<= 1) {
      sxp += __shfl_xor(sxp, msk, 64);
      merge5_shfl(u5, msk);
    }
    // per-wave partials -> LDS tail -> thread 0
    float* R = &S[NM * 577];
    if (lane == 0) {
      R[w] = cpart;
      R[8 + w] = sxp;
#pragma unroll
      for (int k = 0; k < 5; ++k) R[16 + w * 5 + k] = u5[k];
    }
    __syncthreads();
    if (t == 0) {
      float tot = R[0] + R[1] + R[2] + R[3];
      float sp = R[8] + R[9] + R[10] + R[11];
      float f5[5] = {R[16], R[17], R[18], R[19], R[20]};
#pragma unroll
      for (int ww = 1; ww < 4; ++ww) {
        float o[5] = {R[16 + ww * 5], R[17 + ww * 5], R[18 + ww * 5],
                      R[19 + ww * 5], R[20 + ww * 5]};
        merge5(f5, o);
      }
      const float st = f5[0] + f5[1] + f5[2] + f5[3] + f5[4];
      tot += (sp - st) * (0.4f / (float)(NB * NN));
      atomicAdd(out + 2, tot);
    }
    return;
  }

  // ---- block 64: loss_c (CLIP bi-directional CE) + loss_t (triplet) ----
  float* S_ = &S[0];                     // 64 x 65 padded score tile
  for (int i = t; i < 4096; i += 256) S_[(i >> 6) * 65 + (i & 63)] = ws[i];
  __syncthreads();
  float* dgp = &S[4160];
  int* idl = (int*)&S[4224];
  if (t < 64) { dgp[t] = S_[t * 66]; idl[t] = idx[t]; }
  __syncthreads();
  if (t < 64) {                          // exactly wave 0
    const float sc = lscale[0];
    float mR = -FINF, mC = -FINF;
    for (int j = 0; j < 64; ++j) {
      mR = fmaxf(mR, sc * S_[t * 65 + j]);
      mC = fmaxf(mC, sc * S_[j * 65 + t]);
    }
    float seR = 0.f, seC = 0.f;
    for (int j = 0; j < 64; ++j) {
      seR += expf(sc * S_[t * 65 + j] - mR);
      seC += expf(sc * S_[j * 65 + t] - mC);
    }
    const float lseR = mR + logf(seR);
    const float lseC = mC + logf(seC);
    const int myid = idl[t];
    const float di = dgp[t];
    float ps = 0.f, trow = 0.f, tcol = 0.f, cs = 0.f, ci = 0.f;
    for (int j = 0; j < 64; ++j) {
      const float sv = S_[t * 65 + j];
      const float svT = S_[j * 65 + t];
      if (idl[j] == myid) {
        ps += 1.f;
        trow += sc * sv - lseR;
        tcol += sc * svT - lseC;
      }
      if (j != t) {
        cs += fmaxf(0.f, 0.1f + sv - di);
        ci += fmaxf(0.f, 0.1f + sv - dgp[j]);
      }
    }
    float vc = -(trow + tcol) / ps;
    float vt = cs + ci;
#pragma unroll
    for (int msk = 1; msk < 64; msk <<= 1) {
      vc += __shfl_xor(vc, msk, 64);
      vt += __shfl_xor(vt, msk, 64);
    }
    if (t == 0) {
      out[0] = vc * (0.5f / 64.f);
      out[1] = vt * 0.5f;
    }
  }
}

extern "C" void kernel_launch(void* const* d_in, const int* in_sizes, int n_in,
                              void* d_out, int out_size, void* d_ws, size_t ws_size,
                              hipStream_t stream) {
  const float* patch = (const float*)d_in[0];
  const float* noun  = (const float*)d_in[1];
  const float* gimg  = (const float*)d_in[2];
  const float* gtxt  = (const float*)d_in[3];
  const float* lsc   = (const float*)d_in[4];
  const int*   idx   = (const int*)d_in[5];
  float* out = (float*)d_out;
  float* ws  = (float*)d_ws;

  // out[2] accumulated via atomicAdd across k_loss blocks; harness poisons d_out
  hipMemsetAsync(d_out, 0, 3 * sizeof(float), stream);
  k_sim<<<dim3(NBLK1), dim3(256), 0, stream>>>(patch, noun, gimg, gtxt, ws);
  k_loss<<<dim3(NB + 1), dim3(256), 0, stream>>>(ws, lsc, idx, out);
}

// Round 8
// 136.810 us; speedup vs baseline: 3.0781x; 1.0275x over previous
//
#include <hip/hip_runtime.h>
#include <hip/hip_bf16.h>
#include <math.h>

#define NB 64      // batch
#define NN 576     // patches
#define ND 512     // dim
#define NM 16      // nouns
#define QPB 9      // quads per batch element (64 patches each)
#define KPOS 5
#define TINV 14.2857142857142857f   // 1/0.07

#define NFINE (NB * QPB)            // 576 fine blocks
#define NBLK1 (NFINE + NB)          // 640
#define WS_SIM 4096                 // sim tiles after 64x64 scores
#define WS_NOUNF (WS_SIM + NFINE * 1024)   // bf16 noun copy (float offset 593920)

#define FINF __builtin_inff()

typedef __attribute__((ext_vector_type(8))) short short8;   // 8 bf16 (4 VGPRs)
typedef __attribute__((ext_vector_type(4))) float floatx4;  // MFMA C/D

// pack two fp32 into one dword of 2 bf16 by TRUNCATION: single v_perm_b32.
// dst byte0,1 = lo bytes 2,3 (sel 2,3); byte2,3 = hi bytes 2,3 (sel 6,7).
__device__ __forceinline__ unsigned pk2(float lo, float hi) {
  return __builtin_amdgcn_perm(__float_as_uint(hi), __float_as_uint(lo), 0x07060302u);
}

// B-fragment from 8 fp32 (two float4): 4 v_perm total
__device__ __forceinline__ short8 packB(const float4 a, const float4 b) {
  union { unsigned u[4]; short8 s; } cv;
  cv.u[0] = pk2(a.x, a.y);
  cv.u[1] = pk2(a.z, a.w);
  cv.u[2] = pk2(b.x, b.y);
  cv.u[3] = pk2(b.z, b.w);
  return cv.s;
}

// insert v into desc-sorted 5-list (constant indices only -> stays in VGPRs)
__device__ __forceinline__ void ins5(float (&a)[5], float v) {
  if (v > a[4]) {
    a[4] = v;
    if (a[4] > a[3]) { float x = a[4]; a[4] = a[3]; a[3] = x; }
    if (a[3] > a[2]) { float x = a[3]; a[3] = a[2]; a[2] = x; }
    if (a[2] > a[1]) { float x = a[2]; a[2] = a[1]; a[1] = x; }
    if (a[1] > a[0]) { float x = a[1]; a[1] = a[0]; a[0] = x; }
  }
}

// top-5 of union of two desc-sorted 5-lists, branch-free fixed-index rank merge
__device__ __forceinline__ void merge5(float (&a)[5], const float (&b)[5]) {
  float r[5];
#pragma unroll
  for (int k = 0; k < 5; ++k) {
    float best = -FINF;
#pragma unroll
    for (int i = 0; i <= k + 1; ++i) {
      const int j = k + 1 - i;
      const float av = (i == 0) ? FINF : a[i - 1];
      const float bv = (j == 0) ? FINF : b[j - 1];
      best = fmaxf(best, fminf(av, bv));
    }
    r[k] = best;
  }
#pragma unroll
  for (int k = 0; k < 5; ++k) a[k] = r[k];
}

__device__ __forceinline__ void merge5_shfl(float (&a)[5], int msk) {
  float o[5];
#pragma unroll
  for (int k = 0; k < 5; ++k) o[k] = __shfl_xor(a[k], msk, 64);
  merge5(a, o);
}

// ============ kernel 0: noun fp32 -> bf16 (RNE; done once, reused 36x) ============
__global__ __launch_bounds__(256) void k_prep(
    const float* __restrict__ noun, float* __restrict__ ws) {
  const int i = blockIdx.x * 256 + threadIdx.x;   // 131072 threads x 4 floats
  const float4 v = ((const float4*)noun)[i];
  unsigned ux = __float_as_uint(v.x), uy = __float_as_uint(v.y);
  unsigned uz = __float_as_uint(v.z), uw = __float_as_uint(v.w);
  ux += 0x7FFFu + ((ux >> 16) & 1u);
  uy += 0x7FFFu + ((uy >> 16) & 1u);
  uz += 0x7FFFu + ((uz >> 16) & 1u);
  uw += 0x7FFFu + ((uw >> 16) & 1u);
  uint2 o;
  o.x = __builtin_amdgcn_perm(uy, ux, 0x07060302u);
  o.y = __builtin_amdgcn_perm(uw, uz, 0x07060302u);
  ((uint2*)((unsigned short*)(ws + WS_NOUNF)))[i] = o;
}

// ============ kernel 1: sim tiles (bf16 MFMA) + global scores ============
// fine block (b, quad): wave w computes the full-K 16-noun x 16-patch C-tile
// for patches quad*64 + w*16 .. +15. A = pre-converted bf16 noun (1 load/iter,
// zero conversion); B = patch fp32 (2 loads + 4 v_perm truncation packs).
// No LDS, no barriers. unroll 4 bounds VGPRs (R4/R5 lesson: full-unroll load
// hoisting kills occupancy).
__global__ __launch_bounds__(256) void k_sim(
    const float* __restrict__ patch, const float* __restrict__ gimg,
    const float* __restrict__ gtxt, float* __restrict__ ws) {
  const int blk = blockIdx.x;
  const int t = threadIdx.x;
  const int lane = t & 63;

  __shared__ float L[256];   // score path only

  if (blk < NFINE) {
    const int b = blk / QPB, quad = blk - b * QPB;
    const int w = t >> 6;
    const int nidx = lane & 15;          // A: noun row m / B: patch col n
    const int k0 = (lane >> 4) * 8;      // k-offset within 32-wide kstep

    const unsigned short* nrow =
        (const unsigned short*)(ws + WS_NOUNF) + ((size_t)b * NM + nidx) * ND + k0;
    const float* prow =
        patch + ((size_t)(b * NN + quad * 64 + w * 16 + nidx)) * ND + k0;

    floatx4 acc = {0.f, 0.f, 0.f, 0.f};
#pragma unroll 4
    for (int ks = 0; ks < 16; ++ks) {
      const int o = ks * 32;
      const short8 af = *(const short8*)(nrow + o);
      const float4 p0 = *(const float4*)(prow + o);
      const float4 p1 = *(const float4*)(prow + o + 4);
      const short8 bf = packB(p0, p1);
      acc = __builtin_amdgcn_mfma_f32_16x16x32_bf16(af, bf, acc, 0, 0, 0);
    }

    // C/D layout: col(=patch)=lane&15, row(=noun)=(lane>>4)*4+r  [m89-verified]
    float* dst = ws + WS_SIM + (size_t)blk * 1024;
    const int mrow = (lane >> 4) * 4;
    const int pcol = w * 16 + nidx;
#pragma unroll
    for (int r = 0; r < 4; ++r) dst[(mrow + r) * 64 + pcol] = acc[r];
  } else {
    // score block: scores[i][j] = <img_i, txt_j>
    const int i = blk - NFINE;
    const int dq = t >> 6;   // 0..3 d-split (128 floats each)
    const float4* ip = (const float4*)(gimg + (size_t)i * ND + dq * 128);
    const float4* tp = (const float4*)(gtxt + (size_t)lane * ND + dq * 128);
    float a = 0.f;
#pragma unroll
    for (int q = 0; q < 32; ++q) {
      const float4 x = ip[q];
      const float4 y = tp[q];
      a += x.x * y.x + x.y * y.y + x.z * y.z + x.w * y.w;
    }
    L[dq * 64 + lane] = a;
    __syncthreads();
    if (t < 64) ws[i * 64 + t] = L[t] + L[64 + t] + L[128 + t] + L[192 + t];
  }
}

// ============ kernel 2: all losses ============
__global__ __launch_bounds__(256) void k_loss(
    const float* __restrict__ ws, const float* __restrict__ lscale,
    const int* __restrict__ idx, float* __restrict__ out) {
  const int blk = blockIdx.x;
  const int t = threadIdx.x;
  const int lane = t & 63;
  const int w = t >> 6;

  __shared__ float S[NM * 577 + 64];   // 37.2 KB; tail used for reductions

  if (blk < NB) {
    // ---- stage full scaled sim[16][576] for batch b from the 9 quad tiles ----
    const int b = blk;
#pragma unroll
    for (int q = 0; q < QPB; ++q) {
      const float4* t0 = (const float4*)(ws + WS_SIM + (size_t)(b * QPB + q) * 1024);
      const float4 a = t0[t];
      const int i0 = 4 * t;            // element index in 16x64 tile
      const int m = i0 >> 6, p = i0 & 63;
      float* dst = &S[m * 577 + q * 64 + p];
      dst[0] = a.x * TINV;
      dst[1] = a.y * TINV;
      dst[2] = a.z * TINV;
      dst[3] = a.w * TINV;
    }
    __syncthreads();

    // ---- per-noun contrastive: wave w handles m = 4w..4w+3 over 576 cols ----
    float cpart = 0.f;
#pragma unroll
    for (int mi = 0; mi < 4; ++mi) {
      const int m = w * 4 + mi;
      const float* row = &S[m * 577];
      float mx = -FINF;
#pragma unroll
      for (int k = 0; k < 9; ++k) mx = fmaxf(mx, row[lane + 64 * k]);
#pragma unroll
      for (int msk = 1; msk < 64; msk <<= 1) mx = fmaxf(mx, __shfl_xor(mx, msk, 64));
      float se = 0.f;
      float t5[5] = {-FINF, -FINF, -FINF, -FINF, -FINF};
#pragma unroll
      for (int k = 0; k < 9; ++k) {
        const float v = row[lane + 64 * k];
        se += expf(v - mx);
        ins5(t5, v);
      }
#pragma unroll
      for (int msk = 1; msk < 64; msk <<= 1) {
        se += __shfl_xor(se, msk, 64);
        merge5_shfl(t5, msk);
      }
      if (lane == 0) {
        const float st = t5[0] + t5[1] + t5[2] + t5[3] + t5[4];
        cpart += (KPOS * (mx + logf(se)) - st) * (0.6f / (float)(NB * NM));
      }
    }

    // ---- mask loss: pooled/T = column mean; softplus sum + top5 ----
    float sxp = 0.f;
    float u5[5] = {-FINF, -FINF, -FINF, -FINF, -FINF};
#pragma unroll
    for (int rep = 0; rep < 3; ++rep) {
      const int n = t + rep * 256;
      if (n < NN) {
        float cs = 0.f;
#pragma unroll
        for (int m = 0; m < NM; ++m) cs += S[m * 577 + n];
        const float x = cs * (1.f / 16.f);
        sxp += (x > 0.f) ? (x + log1pf(expf(-x))) : log1pf(expf(x));
        ins5(u5, x);
      }
    }
#pragma unroll
    for (int msk = 1; msk < 64; msk <<= 1) {
      sxp += __shfl_xor(sxp, msk, 64);
      merge5_shfl(u5, msk);
    }
    // per-wave partials -> LDS tail -> thread 0
    float* R = &S[NM * 577];
    if (lane == 0) {
      R[w] = cpart;
      R[8 + w] = sxp;
#pragma unroll
      for (int k = 0; k < 5; ++k) R[16 + w * 5 + k] = u5[k];
    }
    __syncthreads();
    if (t == 0) {
      float tot = R[0] + R[1] + R[2] + R[3];
      float sp = R[8] + R[9] + R[10] + R[11];
      float f5[5] = {R[16], R[17], R[18], R[19], R[20]};
#pragma unroll
      for (int ww = 1; ww < 4; ++ww) {
        float o[5] = {R[16 + ww * 5], R[17 + ww * 5], R[18 + ww * 5],
                      R[19 + ww * 5], R[20 + ww * 5]};
        merge5(f5, o);
      }
      const float st = f5[0] + f5[1] + f5[2] + f5[3] + f5[4];
      tot += (sp - st) * (0.4f / (float)(NB * NN));
      atomicAdd(out + 2, tot);
    }
    return;
  }

  // ---- block 64: loss_c (CLIP bi-directional CE) + loss_t (triplet) ----
  float* S_ = &S[0];                     // 64 x 65 padded score tile
  for (int i = t; i < 4096; i += 256) S_[(i >> 6) * 65 + (i & 63)] = ws[i];
  __syncthreads();
  float* dgp = &S[4160];
  int* idl = (int*)&S[4224];
  if (t < 64) { dgp[t] = S_[t * 66]; idl[t] = idx[t]; }
  __syncthreads();
  if (t < 64) {                          // exactly wave 0
    const float sc = lscale[0];
    float mR = -FINF, mC = -FINF;
    for (int j = 0; j < 64; ++j) {
      mR = fmaxf(mR, sc * S_[t * 65 + j]);
      mC = fmaxf(mC, sc * S_[j * 65 + t]);
    }
    float seR = 0.f, seC = 0.f;
    for (int j = 0; j < 64; ++j) {
      seR += expf(sc * S_[t * 65 + j] - mR);
      seC += expf(sc * S_[j * 65 + t] - mC);
    }
    const float lseR = mR + logf(seR);
    const float lseC = mC + logf(seC);
    const int myid = idl[t];
    const float di = dgp[t];
    float ps = 0.f, trow = 0.f, tcol = 0.f, cs = 0.f, ci = 0.f;
    for (int j = 0; j < 64; ++j) {
      const float sv = S_[t * 65 + j];
      const float svT = S_[j * 65 + t];
      if (idl[j] == myid) {
        ps += 1.f;
        trow += sc * sv - lseR;
        tcol += sc * svT - lseC;
      }
      if (j != t) {
        cs += fmaxf(0.f, 0.1f + sv - di);
        ci += fmaxf(0.f, 0.1f + sv - dgp[j]);
      }
    }
    float vc = -(trow + tcol) / ps;
    float vt = cs + ci;
#pragma unroll
    for (int msk = 1; msk < 64; msk <<= 1) {
      vc += __shfl_xor(vc, msk, 64);
      vt += __shfl_xor(vt, msk, 64);
    }
    if (t == 0) {
      out[0] = vc * (0.5f / 64.f);
      out[1] = vt * 0.5f;
    }
  }
}

extern "C" void kernel_launch(void* const* d_in, const int* in_sizes, int n_in,
                              void* d_out, int out_size, void* d_ws, size_t ws_size,
                              hipStream_t stream) {
  const float* patch = (const float*)d_in[0];
  const float* noun  = (const float*)d_in[1];
  const float* gimg  = (const float*)d_in[2];
  const float* gtxt  = (const float*)d_in[3];
  const float* lsc   = (const float*)d_in[4];
  const int*   idx   = (const int*)d_in[5];
  float* out = (float*)d_out;
  float* ws  = (float*)d_ws;

  // out[2] accumulated via atomicAdd across k_loss blocks; harness poisons d_out
  hipMemsetAsync(d_out, 0, 3 * sizeof(float), stream);
  k_prep<<<dim3(512), dim3(256), 0, stream>>>(noun, ws);
  k_sim<<<dim3(NBLK1), dim3(256), 0, stream>>>(patch, gimg, gtxt, ws);
  k_loss<<<dim3(NB + 1), dim3(256), 0, stream>>>(ws, lsc, idx, out);
}

// Round 9
// 136.082 us; speedup vs baseline: 3.0946x; 1.0054x over previous
//
#include <hip/hip_runtime.h>
#include <hip/hip_bf16.h>
#include <math.h>

#define NB 64      // batch
#define NN 576     // patches
#define ND 512     // dim
#define NM 16      // nouns
#define QPB 9      // quads per batch element (64 patches each)
#define KPOS 5
#define TINV 14.2857142857142857f   // 1/0.07

#define NFINE (NB * QPB)            // 576 fine blocks
#define NBLK1 (NFINE + NB)          // 640
#define WS_REC_OFF 4096             // records after 64x64 scores
#define RECSZ 144                   // floats per fine-block record
#define WS_NOUNF (WS_REC_OFF + NFINE * RECSZ)   // bf16 noun copy (float off 87040)

#define FINF __builtin_inff()

typedef __attribute__((ext_vector_type(8))) short short8;   // 8 bf16 (4 VGPRs)
typedef __attribute__((ext_vector_type(4))) float floatx4;  // MFMA C/D

// pack two fp32 into one dword of 2 bf16 by TRUNCATION: single v_perm_b32
__device__ __forceinline__ unsigned pk2(float lo, float hi) {
  return __builtin_amdgcn_perm(__float_as_uint(hi), __float_as_uint(lo), 0x07060302u);
}

__device__ __forceinline__ short8 packB(const float4 a, const float4 b) {
  union { unsigned u[4]; short8 s; } cv;
  cv.u[0] = pk2(a.x, a.y);
  cv.u[1] = pk2(a.z, a.w);
  cv.u[2] = pk2(b.x, b.y);
  cv.u[3] = pk2(b.z, b.w);
  return cv.s;
}

// insert v into desc-sorted 5-list (constant indices only -> stays in VGPRs)
__device__ __forceinline__ void ins5(float (&a)[5], float v) {
  if (v > a[4]) {
    a[4] = v;
    if (a[4] > a[3]) { float x = a[4]; a[4] = a[3]; a[3] = x; }
    if (a[3] > a[2]) { float x = a[3]; a[3] = a[2]; a[2] = x; }
    if (a[2] > a[1]) { float x = a[2]; a[2] = a[1]; a[1] = x; }
    if (a[1] > a[0]) { float x = a[1]; a[1] = a[0]; a[0] = x; }
  }
}

// top-5 of union of two desc-sorted 5-lists, branch-free fixed-index rank merge
__device__ __forceinline__ void merge5(float (&a)[5], const float (&b)[5]) {
  float r[5];
#pragma unroll
  for (int k = 0; k < 5; ++k) {
    float best = -FINF;
#pragma unroll
    for (int i = 0; i <= k + 1; ++i) {
      const int j = k + 1 - i;
      const float av = (i == 0) ? FINF : a[i - 1];
      const float bv = (j == 0) ? FINF : b[j - 1];
      best = fmaxf(best, fminf(av, bv));
    }
    r[k] = best;
  }
#pragma unroll
  for (int k = 0; k < 5; ++k) a[k] = r[k];
}

__device__ __forceinline__ void merge5_shfl(float (&a)[5], int msk) {
  float o[5];
#pragma unroll
  for (int k = 0; k < 5; ++k) o[k] = __shfl_xor(a[k], msk, 64);
  merge5(a, o);
}

// ============ kernel 0: noun fp32 -> bf16 (RNE; done once, reused 36x) ============
__global__ __launch_bounds__(256) void k_prep(
    const float* __restrict__ noun, float* __restrict__ ws) {
  const int i = blockIdx.x * 256 + threadIdx.x;   // 131072 threads x 4 floats
  const float4 v = ((const float4*)noun)[i];
  unsigned ux = __float_as_uint(v.x), uy = __float_as_uint(v.y);
  unsigned uz = __float_as_uint(v.z), uw = __float_as_uint(v.w);
  ux += 0x7FFFu + ((ux >> 16) & 1u);
  uy += 0x7FFFu + ((uy >> 16) & 1u);
  uz += 0x7FFFu + ((uz >> 16) & 1u);
  uw += 0x7FFFu + ((uw >> 16) & 1u);
  uint2 o;
  o.x = __builtin_amdgcn_perm(uy, ux, 0x07060302u);
  o.y = __builtin_amdgcn_perm(uw, uz, 0x07060302u);
  ((uint2*)((unsigned short*)(ws + WS_NOUNF)))[i] = o;
}

// ============ kernel 1: MFMA sim tile + per-quad partial records + scores ============
// fine block (b, quad): wave w computes the 16-noun x 16-patch C-tile for
// patches quad*64 + w*16..+15 (fragments straight from global; no staging).
// Epilogue (R2-verified): tile -> LDS, wave0 = per-noun row stats over 64
// cols, wave1 = mask partials; 144-float record to ws.
__global__ __launch_bounds__(256) void k_sim(
    const float* __restrict__ patch, const float* __restrict__ gimg,
    const float* __restrict__ gtxt, float* __restrict__ ws) {
  const int blk = blockIdx.x;
  const int t = threadIdx.x;
  const int lane = t & 63;

  __shared__ float S[NM * 65];   // 4160 B: scaled sim tile (score path reuses head)

  if (blk < NFINE) {
    const int b = blk / QPB, quad = blk - b * QPB;
    const int w = t >> 6;
    const int nidx = lane & 15;          // A: noun row m / B: patch col n
    const int k0 = (lane >> 4) * 8;      // k-offset within 32-wide kstep

    const unsigned short* nrow =
        (const unsigned short*)(ws + WS_NOUNF) + ((size_t)b * NM + nidx) * ND + k0;
    const float* prow =
        patch + ((size_t)(b * NN + quad * 64 + w * 16 + nidx)) * ND + k0;

    floatx4 acc = {0.f, 0.f, 0.f, 0.f};
#pragma unroll 4
    for (int ks = 0; ks < 16; ++ks) {
      const int o = ks * 32;
      const short8 af = *(const short8*)(nrow + o);
      const float4 p0 = *(const float4*)(prow + o);
      const float4 p1 = *(const float4*)(prow + o + 4);
      const short8 bf = packB(p0, p1);
      acc = __builtin_amdgcn_mfma_f32_16x16x32_bf16(af, bf, acc, 0, 0, 0);
    }

    // C/D layout: col(=patch)=lane&15, row(=noun)=(lane>>4)*4+r  [m89-verified]
    const int mrow = (lane >> 4) * 4;
    const int pcol = w * 16 + nidx;
#pragma unroll
    for (int r = 0; r < 4; ++r) S[(mrow + r) * 65 + pcol] = acc[r] * TINV;
    __syncthreads();

    float* rec = ws + WS_REC_OFF + (size_t)blk * RECSZ;
    if (w == 1) {
      // ---- mask partials: softplus sum + top5 of pooled/T over 64 patches ----
      float x = 0.f;
#pragma unroll
      for (int m = 0; m < NM; ++m) x += S[m * 65 + lane];
      x *= (1.f / 16.f);
      float sxp = (x > 0.f) ? (x + log1pf(expf(-x))) : log1pf(expf(x));
      float t5[5] = {x, -FINF, -FINF, -FINF, -FINF};
#pragma unroll
      for (int msk = 1; msk < 64; msk <<= 1) {
        sxp += __shfl_xor(sxp, msk, 64);
        merge5_shfl(t5, msk);
      }
      if (lane == 0) {
        rec[128] = sxp;
#pragma unroll
        for (int k = 0; k < 5; ++k) rec[129 + k] = t5[k];
      }
    } else if (w == 0) {
      // ---- per-noun row stats over 64 cols (16 rows x 4 segments) ----
      const int r_ = lane & 15;
      const int h = lane >> 4;
      const float* row = &S[r_ * 65 + h * 16];
      float mx = -FINF;
#pragma unroll
      for (int k = 0; k < 16; ++k) mx = fmaxf(mx, row[k]);
      mx = fmaxf(mx, __shfl_xor(mx, 16, 64));
      mx = fmaxf(mx, __shfl_xor(mx, 32, 64));
      float se = 0.f;
      float r5[5] = {-FINF, -FINF, -FINF, -FINF, -FINF};
#pragma unroll
      for (int k = 0; k < 16; ++k) {
        const float v = row[k];
        se += expf(v - mx);
        ins5(r5, v);
      }
      se += __shfl_xor(se, 16, 64);
      se += __shfl_xor(se, 32, 64);
      merge5_shfl(r5, 16);
      merge5_shfl(r5, 32);
      if (h == 0) {
        float* rr = rec + r_ * 8;
        rr[0] = mx;
        rr[1] = se;
#pragma unroll
        for (int k = 0; k < 5; ++k) rr[2 + k] = r5[k];
      }
    }
  } else {
    // score block: scores[i][j] = <img_i, txt_j>
    const int i = blk - NFINE;
    const int dq = t >> 6;   // 0..3 d-split (128 floats each)
    const float4* ip = (const float4*)(gimg + (size_t)i * ND + dq * 128);
    const float4* tp = (const float4*)(gtxt + (size_t)lane * ND + dq * 128);
    float a = 0.f;
#pragma unroll
    for (int q = 0; q < 32; ++q) {
      const float4 x = ip[q];
      const float4 y = tp[q];
      a += x.x * y.x + x.y * y.y + x.z * y.z + x.w * y.w;
    }
    S[dq * 64 + lane] = a;
    __syncthreads();
    if (t < 64) ws[i * 64 + t] = S[t] + S[64 + t] + S[128 + t] + S[192 + t];
  }
}

// ============ kernel 2: merge records (R2-verified) + CLIP/triplet ============
__global__ __launch_bounds__(64) void k_final(
    const float* __restrict__ ws, const float* __restrict__ lscale,
    const int* __restrict__ idx, float* __restrict__ out) {
  const int blk = blockIdx.x;
  const int t = threadIdx.x;

  if (blk < NB) {
    // ---- merge the 9 quad partials for batch element blk (lane-parallel) ----
    const float* base = ws + WS_REC_OFF + (size_t)blk * QPB * RECSZ;
    const int m = t & 15;
    const int g = t >> 4;               // quad group: g gets quads {g, g+4, (g==0: 8)}
    const int nq = (g == 0) ? 3 : 2;

    float lm[3], ls[3];
    float t5[5] = {-FINF, -FINF, -FINF, -FINF, -FINF};
#pragma unroll
    for (int i = 0; i < 3; ++i) { lm[i] = -FINF; ls[i] = 0.f; }
    float mx = -FINF;
    for (int i = 0; i < nq; ++i) {
      const float* rr = base + (g + 4 * i) * RECSZ + m * 8;
      lm[i] = rr[0]; ls[i] = rr[1];
      mx = fmaxf(mx, rr[0]);
#pragma unroll
      for (int k = 0; k < 5; ++k) ins5(t5, rr[2 + k]);
    }
    mx = fmaxf(mx, __shfl_xor(mx, 16, 64));
    mx = fmaxf(mx, __shfl_xor(mx, 32, 64));
    float S = 0.f;
    for (int i = 0; i < nq; ++i) S += ls[i] * expf(lm[i] - mx);
    S += __shfl_xor(S, 16, 64);
    S += __shfl_xor(S, 32, 64);
    merge5_shfl(t5, 16);
    merge5_shfl(t5, 32);

    float contrib = 0.f;
    if (g == 0) {
      const float lse = mx + logf(S);
      const float st = t5[0] + t5[1] + t5[2] + t5[3] + t5[4];
      contrib = (KPOS * lse - st) * (0.6f / (float)(NB * NM));
    }

    // mask partials on lanes with m==0 (g-split over quads, reduce across g)
    float sp_ = 0.f;
    float u5[5] = {-FINF, -FINF, -FINF, -FINF, -FINF};
    if (m == 0) {
      for (int i = 0; i < nq; ++i) {
        const float* rr = base + (g + 4 * i) * RECSZ + 128;
        sp_ += rr[0];
#pragma unroll
        for (int k = 0; k < 5; ++k) ins5(u5, rr[1 + k]);
      }
    }
    sp_ += __shfl_xor(sp_, 16, 64);
    sp_ += __shfl_xor(sp_, 32, 64);
    merge5_shfl(u5, 16);
    merge5_shfl(u5, 32);
    if (t == 0) {
      const float st = u5[0] + u5[1] + u5[2] + u5[3] + u5[4];
      contrib += (sp_ - st) * (0.4f / (float)(NB * NN));
    }
#pragma unroll
    for (int msk = 1; msk < 64; msk <<= 1) contrib += __shfl_xor(contrib, msk, 64);
    if (t == 0) atomicAdd(out + 2, contrib);
    return;
  }

  // ---- loss_c (CLIP bi-directional CE) + loss_t (triplet), from scores ----
  __shared__ float s[64 * 65];
  __shared__ float dg[64];
  __shared__ int idl[64];
  for (int i = 0; i < 64; ++i) s[i * 65 + t] = ws[i * 64 + t];
  idl[t] = idx[t];
  __syncthreads();
  dg[t] = s[t * 66];
  __syncthreads();
  const float sc = lscale[0];

  float mR = -FINF, mC = -FINF;
  for (int j = 0; j < 64; ++j) {
    mR = fmaxf(mR, sc * s[t * 65 + j]);
    mC = fmaxf(mC, sc * s[j * 65 + t]);
  }
  float seR = 0.f, seC = 0.f;
  for (int j = 0; j < 64; ++j) {
    seR += expf(sc * s[t * 65 + j] - mR);
    seC += expf(sc * s[j * 65 + t] - mC);
  }
  const float lseR = mR + logf(seR);
  const float lseC = mC + logf(seC);

  const int myid = idl[t];
  const float di = dg[t];
  float ps = 0.f, trow = 0.f, tcol = 0.f, cs = 0.f, ci = 0.f;
  for (int j = 0; j < 64; ++j) {
    const float sv = s[t * 65 + j];
    const float svT = s[j * 65 + t];
    if (idl[j] == myid) {
      ps += 1.f;
      trow += sc * sv - lseR;
      tcol += sc * svT - lseC;
    }
    if (j != t) {
      cs += fmaxf(0.f, 0.1f + sv - di);
      ci += fmaxf(0.f, 0.1f + sv - dg[j]);
    }
  }
  float vc = -(trow + tcol) / ps;
  float vt = cs + ci;
#pragma unroll
  for (int msk = 1; msk < 64; msk <<= 1) {
    vc += __shfl_xor(vc, msk, 64);
    vt += __shfl_xor(vt, msk, 64);
  }
  if (t == 0) {
    out[0] = vc * (0.5f / 64.f);
    out[1] = vt * 0.5f;
  }
}

extern "C" void kernel_launch(void* const* d_in, const int* in_sizes, int n_in,
                              void* d_out, int out_size, void* d_ws, size_t ws_size,
                              hipStream_t stream) {
  const float* patch = (const float*)d_in[0];
  const float* noun  = (const float*)d_in[1];
  const float* gimg  = (const float*)d_in[2];
  const float* gtxt  = (const float*)d_in[3];
  const float* lsc   = (const float*)d_in[4];
  const int*   idx   = (const int*)d_in[5];
  float* out = (float*)d_out;
  float* ws  = (float*)d_ws;

  // out[2] accumulated via atomicAdd across k_final blocks; harness poisons d_out
  hipMemsetAsync(d_out, 0, 3 * sizeof(float), stream);
  k_prep<<<dim3(512), dim3(256), 0, stream>>>(noun, ws);
  k_sim<<<dim3(NBLK1), dim3(256), 0, stream>>>(patch, gimg, gtxt, ws);
  k_final<<<dim3(NB + 1), dim3(64), 0, stream>>>(ws, lsc, idx, out);
}